// Round 1
// baseline (14302.235 us; speedup 1.0000x reference)
//
#include <hip/hip_runtime.h>
#include <stdint.h>
#include <stddef.h>

#define VOCAB 32000
#define HID   1024
#define BATCH 256
#define SEQ   512
#define G3    3072
#define NBLK  256

typedef unsigned short u16;
typedef short bf16x8 __attribute__((ext_vector_type(8)));
typedef float f32x4 __attribute__((ext_vector_type(4)));
typedef u16   u16x4 __attribute__((ext_vector_type(4)));

typedef void __attribute__((address_space(1))) gvoid;
typedef void __attribute__((address_space(3))) lvoid;

__device__ __forceinline__ u16 f2b(float f) {
  union { float f; unsigned u; } x; x.f = f;
  return (u16)((x.u + 0x7fffu + ((x.u >> 16) & 1u)) >> 16);
}
__device__ __forceinline__ float b2f(u16 u) {
  union { unsigned u; float f; } x; x.u = ((unsigned)u) << 16;
  return x.f;
}
__device__ __forceinline__ float sigmf(float x) { return 1.0f / (1.0f + __expf(-x)); }
__device__ __forceinline__ float tanhft(float x) { return 1.0f - 2.0f / (__expf(2.0f * x) + 1.0f); }

__device__ __forceinline__ void glds16(const void* g, void* l) {
  __builtin_amdgcn_global_load_lds((gvoid*)g, (lvoid*)l, 16, 0, 0);
}

// ---------------- Phase A0: fp32 -> bf16 conversion ----------------
__global__ __launch_bounds__(256) void cvt_kernel(const float* __restrict__ s,
                                                  u16* __restrict__ d, int n) {
  const int i = (blockIdx.x * 256 + threadIdx.x) * 4;
  if (i + 3 < n) {
    const f32x4 v = *(const f32x4*)(s + i);
    u16x4 o;
    o.x = f2b(v.x); o.y = f2b(v.y); o.z = f2b(v.z); o.w = f2b(v.w);
    *(u16x4*)(d + i) = o;
  }
}

// ---------------- Phase A1: emb_proj = emb_b @ Wih_b^T + b_ih (bf16 out) ----------------
// A: [VOCAB][HID] bf16, B: [G3][HID] bf16 (NT gemm), C: [VOCAB][G3] bf16
__global__ __launch_bounds__(256) void embproj_gemm(const u16* __restrict__ A,
                                                    const u16* __restrict__ Bm,
                                                    const float* __restrict__ bias,
                                                    u16* __restrict__ C) {
  __shared__ u16 sA[128 * 32];
  __shared__ u16 sB[128 * 32];
  const int tid = threadIdx.x;
  const int w = tid >> 6, l = tid & 63;
  const int wm = w >> 1, wn = w & 1;
  const int m0 = (int)(blockIdx.x / 24) * 128;
  const int n0 = (int)(blockIdx.x % 24) * 128;
  const int row1 = tid >> 2;        // 0..63
  const int kh1  = tid & 3;         // 16B chunk within 64B row
  const int kin  = (l >> 4) << 3;
  const int lm   = l & 15;

  f32x4 acc[4][4] = {};

  char* sAb = (char*)sA;
  char* sBb = (char*)sB;

  for (int k0 = 0; k0 < HID; k0 += 32) {
    __syncthreads();
    glds16(A + (size_t)(m0 + row1) * HID + k0 + kh1 * 8,       sAb + w * 1024);
    glds16(A + (size_t)(m0 + 64 + row1) * HID + k0 + kh1 * 8,  sAb + 4096 + w * 1024);
    glds16(Bm + (size_t)(n0 + row1) * HID + k0 + kh1 * 8,      sBb + w * 1024);
    glds16(Bm + (size_t)(n0 + 64 + row1) * HID + k0 + kh1 * 8, sBb + 4096 + w * 1024);
    __syncthreads();
    bf16x8 aF[4], bF[4];
#pragma unroll
    for (int mt = 0; mt < 4; ++mt)
      aF[mt] = *(const bf16x8*)&sA[(64 * wm + 16 * mt + lm) * 32 + kin];
#pragma unroll
    for (int nt = 0; nt < 4; ++nt)
      bF[nt] = *(const bf16x8*)&sB[(64 * wn + 16 * nt + lm) * 32 + kin];
#pragma unroll
    for (int mt = 0; mt < 4; ++mt)
#pragma unroll
      for (int nt = 0; nt < 4; ++nt)
        acc[mt][nt] = __builtin_amdgcn_mfma_f32_16x16x32_bf16(aF[mt], bF[nt], acc[mt][nt], 0, 0, 0);
  }
  __syncthreads();
  // epilogue: C layout col = lane&15, row = (lane>>4)*4 + i  (m89/m91 verified)
#pragma unroll
  for (int mt = 0; mt < 4; ++mt)
#pragma unroll
    for (int nt = 0; nt < 4; ++nt) {
      const int col = n0 + 64 * wn + 16 * nt + lm;
      const float bi = bias[col];
      const int rbase = m0 + 64 * wm + 16 * mt + ((l >> 4) << 2);
#pragma unroll
      for (int i = 0; i < 4; ++i)
        C[(size_t)(rbase + i) * G3 + col] = f2b(acc[mt][nt][i] + bi);
    }
}

// ---------------- grid barrier (all 256 blocks resident by construction) ----------------
__device__ __forceinline__ void gsync(unsigned* cnt, unsigned* gen) {
  __syncthreads();
  if (threadIdx.x == 0) {
    __threadfence();  // release: flush h stores device-wide
    unsigned g = __hip_atomic_load(gen, __ATOMIC_RELAXED, __HIP_MEMORY_SCOPE_AGENT);
    unsigned v = __hip_atomic_fetch_add(cnt, 1u, __ATOMIC_ACQ_REL, __HIP_MEMORY_SCOPE_AGENT);
    if (v == (unsigned)(NBLK - 1)) {
      __hip_atomic_store(cnt, 0u, __ATOMIC_RELAXED, __HIP_MEMORY_SCOPE_AGENT);
      __hip_atomic_store(gen, g + 1u, __ATOMIC_RELEASE, __HIP_MEMORY_SCOPE_AGENT);
    } else {
      while (__hip_atomic_load(gen, __ATOMIC_RELAXED, __HIP_MEMORY_SCOPE_AGENT) == g)
        __builtin_amdgcn_s_sleep(1);
    }
    __threadfence();  // acquire: invalidate L1/L2 before reading remote h
  }
  __syncthreads();
}

// ---------------- Phase B: persistent GRU + fused final dense ----------------
// grid = 256 WGs: (mt in [0,4): 64 batch rows) x (jt in [0,64): 16 hidden cols -> 48 gate cols)
// W_hh slice stationary in LDS; K split over the 4 waves; fp32 partial reduce in LDS.
#define PW 52  // padded pbuf row stride (floats)
__global__ __launch_bounds__(256, 1) void gru_persist(
    const int* __restrict__ inputs, const float* __restrict__ Whh,
    const float* __restrict__ bhh, const u16* __restrict__ embproj,
    const float* __restrict__ Wd, const float* __restrict__ bd,
    float* __restrict__ hA, float* __restrict__ hB,
    u16* __restrict__ hAb, u16* __restrict__ hBb,
    unsigned* __restrict__ bar, float* __restrict__ out) {
  extern __shared__ char smem[];
  u16* Wlds = (u16*)smem;                           // [48][1032] bf16
  float* pbuf = (float*)(smem + 48 * 1032 * 2);     // [4][64][PW]
  float* cred = pbuf + 4 * 64 * PW;                 // [8]

  const int tid = threadIdx.x;
  const int w = tid >> 6, l = tid & 63;
  const int bid = blockIdx.x;
  const int mt = (bid & 7) >> 1;                    // XCD-pair clustering of m-tiles
  const int jt = (bid & 1) + ((bid >> 3) << 1);
  const int m0 = mt << 6, j0 = jt << 4;

  // load W_hh slice -> LDS bf16, gate-major rows: r = g*16 + c  <-> W_hh row g*1024 + j0 + c
  for (int q = tid; q < 48 * 256; q += 256) {
    const int r = q >> 8;
    const int col4 = (q & 255) << 2;
    const int grow = (r >> 4) * HID + j0 + (r & 15);
    const f32x4 v = *(const f32x4*)(Whh + (size_t)grow * HID + col4);
    u16x4 o;
    o.x = f2b(v.x); o.y = f2b(v.y); o.z = f2b(v.z); o.w = f2b(v.w);
    *(u16x4*)&Wlds[r * 1032 + col4] = o;
  }
  __syncthreads();

  const int kin = (l >> 4) << 3;
  const int lm = l & 15;
  const int kbase = w << 8;  // 256-wide K slice per wave

  for (int t = 0; t < SEQ; ++t) {
    const u16* hcb  = (t & 1) ? hBb : hAb;
    const float* hcf = (t & 1) ? hB : hA;
    float* hnf = (t & 1) ? hA : hB;
    u16* hnb   = (t & 1) ? hAb : hBb;

    f32x4 acc[4][3] = {};
#pragma unroll
    for (int kk = 0; kk < 8; ++kk) {
      const int k0 = kbase + (kk << 5) + kin;
      bf16x8 aF[4], bF[3];
#pragma unroll
      for (int m = 0; m < 4; ++m)
        aF[m] = *(const bf16x8*)&hcb[(size_t)(m0 + (m << 4) + lm) * HID + k0];
#pragma unroll
      for (int g = 0; g < 3; ++g)
        bF[g] = *(const bf16x8*)&Wlds[((g << 4) + lm) * 1032 + k0];
#pragma unroll
      for (int m = 0; m < 4; ++m)
#pragma unroll
        for (int g = 0; g < 3; ++g)
          acc[m][g] = __builtin_amdgcn_mfma_f32_16x16x32_bf16(aF[m], bF[g], acc[m][g], 0, 0, 0);
    }
    // partials -> LDS
#pragma unroll
    for (int m = 0; m < 4; ++m)
#pragma unroll
      for (int g = 0; g < 3; ++g) {
        const int rb = (m << 4) + ((l >> 4) << 2);
#pragma unroll
        for (int i = 0; i < 4; ++i)
          pbuf[(w * 64 + rb + i) * PW + (g << 4) + lm] = acc[m][g][i];
      }
    __syncthreads();

    // elementwise gates: 64 rows x 16 cols, 4 cells/thread
    {
      const int bl = tid >> 2;
      const int c0 = (tid & 3) << 2;
      const int b = m0 + bl;
      const int tok = inputs[b * SEQ + t];
      f32x4 hr = {}, hz = {}, hn = {};
#pragma unroll
      for (int ww = 0; ww < 4; ++ww) {
        const float* pp = &pbuf[(ww * 64 + bl) * PW];
        hr += *(const f32x4*)(pp + c0);
        hz += *(const f32x4*)(pp + 16 + c0);
        hn += *(const f32x4*)(pp + 32 + c0);
      }
      hr += *(const f32x4*)(bhh + j0 + c0);
      hz += *(const f32x4*)(bhh + HID + j0 + c0);
      hn += *(const f32x4*)(bhh + 2 * HID + j0 + c0);
      const u16x4 xr4 = *(const u16x4*)(embproj + (size_t)tok * G3 + j0 + c0);
      const u16x4 xz4 = *(const u16x4*)(embproj + (size_t)tok * G3 + HID + j0 + c0);
      const u16x4 xn4 = *(const u16x4*)(embproj + (size_t)tok * G3 + 2 * HID + j0 + c0);
      const f32x4 hp = *(const f32x4*)(hcf + (size_t)b * HID + j0 + c0);
      f32x4 hv;
      u16x4 hb;
#pragma unroll
      for (int i = 0; i < 4; ++i) {
        const float r = sigmf(b2f(xr4[i]) + hr[i]);
        const float z = sigmf(b2f(xz4[i]) + hz[i]);
        const float n = tanhft(b2f(xn4[i]) + r * hn[i]);
        const float v2 = (1.0f - z) * n + z * hp[i];
        hv[i] = v2;
        hb[i] = f2b(v2);
      }
      *(f32x4*)(hnf + (size_t)b * HID + j0 + c0) = hv;
      *(u16x4*)(hnb + (size_t)b * HID + j0 + c0) = hb;
    }
    gsync(bar, bar + 32);
  }

  // final dense: h_final is in hA (t=511 odd wrote hA). WG bid -> batch row bid.
  {
    const int b = bid;
    float p0 = 0.f, p1 = 0.f;
    for (int k = tid; k < HID; k += 256) {
      const float hvv = hA[(size_t)b * HID + k];
      p0 += hvv * Wd[k];
      p1 += hvv * Wd[HID + k];
    }
#pragma unroll
    for (int off = 32; off > 0; off >>= 1) {
      p0 += __shfl_down(p0, off);
      p1 += __shfl_down(p1, off);
    }
    if (l == 0) { cred[w] = p0; cred[4 + w] = p1; }
    __syncthreads();
    if (tid == 0) out[2 * b]     = cred[0] + cred[1] + cred[2] + cred[3] + bd[0];
    if (tid == 1) out[2 * b + 1] = cred[4] + cred[5] + cred[6] + cred[7] + bd[1];
  }
}

// ---------------- host launch ----------------
extern "C" void kernel_launch(void* const* d_in, const int* in_sizes, int n_in,
                              void* d_out, int out_size, void* d_ws, size_t ws_size,
                              hipStream_t stream) {
  const int*   inputs = (const int*)d_in[0];
  const float* emb = (const float*)d_in[1];
  const float* Wih = (const float*)d_in[2];
  const float* Whh = (const float*)d_in[3];
  const float* bih = (const float*)d_in[4];
  const float* bhh = (const float*)d_in[5];
  const float* Wd  = (const float*)d_in[6];
  const float* bd  = (const float*)d_in[7];

  char* ws = (char*)d_ws;
  unsigned* bar = (unsigned*)ws;                                  // [0, 256B)
  float* hA = (float*)(ws + (size_t)(1 << 20));                   // 1 MB
  float* hB = (float*)(ws + (size_t)(2 << 20));                   // 1 MB
  u16* hAb  = (u16*)(ws + (size_t)(3 << 20));                     // 512 KB
  u16* hBb  = (u16*)(ws + (size_t)(3 << 20) + (size_t)(1 << 19)); // 512 KB
  u16* embproj = (u16*)(ws + (size_t)(4 << 20));                  // 196,608,000 B
  u16* embb = (u16*)(ws + 4194304ull + 196608000ull);             // 65,536,000 B
  u16* Wihb = (u16*)(ws + 4194304ull + 196608000ull + 65536000ull); // 6,291,456 B

  // zero barrier + h double buffers (h0 = 0 required)
  hipMemsetAsync(d_ws, 0, (size_t)(4 << 20), stream);

  cvt_kernel<<<32000, 256, 0, stream>>>(emb, embb, VOCAB * HID);
  cvt_kernel<<<3072, 256, 0, stream>>>(Wih, Wihb, G3 * HID);
  embproj_gemm<<<250 * 24, 256, 0, stream>>>(embb, Wihb, bih, embproj);

  const int smem_bytes = 48 * 1032 * 2 + 4 * 64 * PW * 4 + 64;  // 152,384 B
  (void)hipFuncSetAttribute((const void*)gru_persist,
                            hipFuncAttributeMaxDynamicSharedMemorySize, smem_bytes);
  gru_persist<<<NBLK, 256, smem_bytes, stream>>>(inputs, Whh, bhh, embproj, Wd, bd,
                                                 hA, hB, hAb, hBb, bar, (float*)d_out);
}

// Round 2
// 10438.767 us; speedup vs baseline: 1.3701x; 1.3701x over previous
//
#include <hip/hip_runtime.h>
#include <stdint.h>
#include <stddef.h>

#define VOCAB 32000
#define HID   1024
#define BATCH 256
#define SEQ   512
#define G3    3072

// gru partitioning: 8 independent groups (heuristically one per XCD via bid&7),
// each group = 32 WGs x (32 batch rows, full 3072 gate cols; 32 hidden cols/WG)
#define GRP   8
#define GWG   32
#define MROWS 32
#define PW    100   // pbuf row stride (floats): 96 cols + 4 pad

typedef unsigned short u16;
typedef short bf16x8 __attribute__((ext_vector_type(8)));
typedef float f32x4 __attribute__((ext_vector_type(4)));
typedef u16   u16x4 __attribute__((ext_vector_type(4)));

typedef void __attribute__((address_space(1))) gvoid;
typedef void __attribute__((address_space(3))) lvoid;

__device__ __forceinline__ u16 f2b(float f) {
  union { float f; unsigned u; } x; x.f = f;
  return (u16)((x.u + 0x7fffu + ((x.u >> 16) & 1u)) >> 16);
}
__device__ __forceinline__ float b2f(u16 u) {
  union { unsigned u; float f; } x; x.u = ((unsigned)u) << 16;
  return x.f;
}
__device__ __forceinline__ float sigmf(float x) { return 1.0f / (1.0f + __expf(-x)); }
__device__ __forceinline__ float tanhft(float x) { return 1.0f - 2.0f / (__expf(2.0f * x) + 1.0f); }

__device__ __forceinline__ void glds16(const void* g, void* l) {
  __builtin_amdgcn_global_load_lds((gvoid*)g, (lvoid*)l, 16, 0, 0);
}

// ---------------- Phase A0: fp32 -> bf16 conversion ----------------
__global__ __launch_bounds__(256) void cvt_kernel(const float* __restrict__ s,
                                                  u16* __restrict__ d, int n) {
  const int i = (blockIdx.x * 256 + threadIdx.x) * 4;
  if (i + 3 < n) {
    const f32x4 v = *(const f32x4*)(s + i);
    u16x4 o;
    o.x = f2b(v.x); o.y = f2b(v.y); o.z = f2b(v.z); o.w = f2b(v.w);
    *(u16x4*)(d + i) = o;
  }
}

// ---------------- Phase A1: emb_proj = emb_b @ Wih_b^T + b_ih (bf16 out) ----------------
__global__ __launch_bounds__(256) void embproj_gemm(const u16* __restrict__ A,
                                                    const u16* __restrict__ Bm,
                                                    const float* __restrict__ bias,
                                                    u16* __restrict__ C) {
  __shared__ u16 sA[128 * 32];
  __shared__ u16 sB[128 * 32];
  const int tid = threadIdx.x;
  const int w = tid >> 6, l = tid & 63;
  const int wm = w >> 1, wn = w & 1;
  const int m0 = (int)(blockIdx.x / 24) * 128;
  const int n0 = (int)(blockIdx.x % 24) * 128;
  const int row1 = tid >> 2;
  const int kh1  = tid & 3;
  const int kin  = (l >> 4) << 3;
  const int lm   = l & 15;

  f32x4 acc[4][4] = {};
  char* sAb = (char*)sA;
  char* sBb = (char*)sB;

  for (int k0 = 0; k0 < HID; k0 += 32) {
    __syncthreads();
    glds16(A + (size_t)(m0 + row1) * HID + k0 + kh1 * 8,       sAb + w * 1024);
    glds16(A + (size_t)(m0 + 64 + row1) * HID + k0 + kh1 * 8,  sAb + 4096 + w * 1024);
    glds16(Bm + (size_t)(n0 + row1) * HID + k0 + kh1 * 8,      sBb + w * 1024);
    glds16(Bm + (size_t)(n0 + 64 + row1) * HID + k0 + kh1 * 8, sBb + 4096 + w * 1024);
    __syncthreads();
    bf16x8 aF[4], bF[4];
#pragma unroll
    for (int mt = 0; mt < 4; ++mt)
      aF[mt] = *(const bf16x8*)&sA[(64 * wm + 16 * mt + lm) * 32 + kin];
#pragma unroll
    for (int nt = 0; nt < 4; ++nt)
      bF[nt] = *(const bf16x8*)&sB[(64 * wn + 16 * nt + lm) * 32 + kin];
#pragma unroll
    for (int mt = 0; mt < 4; ++mt)
#pragma unroll
      for (int nt = 0; nt < 4; ++nt)
        acc[mt][nt] = __builtin_amdgcn_mfma_f32_16x16x32_bf16(aF[mt], bF[nt], acc[mt][nt], 0, 0, 0);
  }
  __syncthreads();
#pragma unroll
  for (int mt = 0; mt < 4; ++mt)
#pragma unroll
    for (int nt = 0; nt < 4; ++nt) {
      const int col = n0 + 64 * wn + 16 * nt + lm;
      const float bi = bias[col];
      const int rbase = m0 + 64 * wm + 16 * mt + ((l >> 4) << 2);
#pragma unroll
      for (int i = 0; i < 4; ++i)
        C[(size_t)(rbase + i) * G3 + col] = f2b(acc[mt][nt][i] + bi);
    }
}

// ---------------- Phase B: persistent GRU, per-group flag barrier ----------------
__global__ __launch_bounds__(256, 1) void gru_persist(
    const int* __restrict__ inputs, const float* __restrict__ Whh,
    const float* __restrict__ bhh, const u16* __restrict__ embproj,
    const float* __restrict__ Wd, const float* __restrict__ bd,
    float* __restrict__ hA, float* __restrict__ hB,
    u16* __restrict__ hAb, u16* __restrict__ hBb,
    unsigned* __restrict__ flags, float* __restrict__ out) {
  __shared__ float pbuf[4 * MROWS * PW + 16];  // 51.3 KB

  const int tid = threadIdx.x;
  const int w = tid >> 6, l = tid & 63;
  const int lm = l & 15, kin = (l >> 4) << 3;
  const int bid = blockIdx.x;
  const int g  = bid & 7;    // group (heuristic: XCD id)
  const int ig = bid >> 3;   // 0..31 within group
  const int m0 = g * MROWS;
  const int j0 = ig * 32;    // 32 hidden cols per WG -> 96 gate cols
  unsigned* gflags = flags + g * 64;  // groups 256B apart

  // ---- preload W_hh fragments into registers: 6 col-frags x 8 kk (192 VGPRs) ----
  const int kb = w << 8;  // 256-wide K slice per wave
  bf16x8 wf[6][8];
#pragma unroll
  for (int gg = 0; gg < 6; ++gg) {
    const int gate = gg >> 1;
    const size_t wrow = (size_t)(gate * HID + j0 + ((gg & 1) << 4) + lm) * HID;
#pragma unroll
    for (int kk = 0; kk < 8; ++kk) {
      const float* p = Whh + wrow + kb + (kk << 5) + kin;
      const f32x4 v0 = *(const f32x4*)p;
      const f32x4 v1 = *(const f32x4*)(p + 4);
      bf16x8 f;
      f[0] = (short)f2b(v0.x); f[1] = (short)f2b(v0.y);
      f[2] = (short)f2b(v0.z); f[3] = (short)f2b(v0.w);
      f[4] = (short)f2b(v1.x); f[5] = (short)f2b(v1.y);
      f[6] = (short)f2b(v1.z); f[7] = (short)f2b(v1.w);
      wf[gg][kk] = f;
    }
  }

  // ---- elementwise-phase constants ----
  const int er = tid >> 3;         // row 0..31
  const int ec = (tid & 7) << 2;   // col 0,4,..,28 within 32-col slice
  const int b  = m0 + er;
  const f32x4 brv = *(const f32x4*)(bhh + j0 + ec);
  const f32x4 bzv = *(const f32x4*)(bhh + HID + j0 + ec);
  const f32x4 bnv = *(const f32x4*)(bhh + 2 * HID + j0 + ec);

  for (int t = 0; t < SEQ; ++t) {
    const u16*  hcb = (t & 1) ? hBb : hAb;
    const float* hcf = (t & 1) ? hB : hA;
    float* hnf = (t & 1) ? hA : hB;
    u16*   hnb = (t & 1) ? hAb : hBb;

    // hoisted gathers (hide L3 latency behind GEMM)
    const int tok = inputs[b * SEQ + t];
    const u16x4 xr4 = *(const u16x4*)(embproj + (size_t)tok * G3 + j0 + ec);
    const u16x4 xz4 = *(const u16x4*)(embproj + (size_t)tok * G3 + HID + j0 + ec);
    const u16x4 xn4 = *(const u16x4*)(embproj + (size_t)tok * G3 + 2 * HID + j0 + ec);
    const f32x4 hp  = *(const f32x4*)(hcf + (size_t)b * HID + j0 + ec);

    // all A fragments up front (2 m x 8 kk = 64 VGPRs) to hide L2 latency
    bf16x8 aF[2][8];
#pragma unroll
    for (int m = 0; m < 2; ++m)
#pragma unroll
      for (int kk = 0; kk < 8; ++kk)
        aF[m][kk] = *(const bf16x8*)&hcb[(size_t)(m0 + (m << 4) + lm) * HID + kb + (kk << 5) + kin];

    f32x4 acc[2][6] = {};
#pragma unroll
    for (int kk = 0; kk < 8; ++kk)
#pragma unroll
      for (int m = 0; m < 2; ++m)
#pragma unroll
        for (int gg = 0; gg < 6; ++gg)
          acc[m][gg] = __builtin_amdgcn_mfma_f32_16x16x32_bf16(aF[m][kk], wf[gg][kk], acc[m][gg], 0, 0, 0);

    // partials -> LDS (C layout: col=lane&15, row=(lane>>4)*4+i)
#pragma unroll
    for (int m = 0; m < 2; ++m)
#pragma unroll
      for (int gg = 0; gg < 6; ++gg) {
        const int rl = (m << 4) + ((l >> 4) << 2);
        const int cl = ((gg >> 1) << 5) + ((gg & 1) << 4) + lm;
#pragma unroll
        for (int i = 0; i < 4; ++i)
          pbuf[(w * MROWS + rl + i) * PW + cl] = acc[m][gg][i];
      }
    __syncthreads();

    // cross-wave reduce + gates (32 rows x 32 cols, 4 cells/thread)
    f32x4 hr = brv, hz = bzv, hn = bnv;
#pragma unroll
    for (int ww = 0; ww < 4; ++ww) {
      const float* pp = &pbuf[(ww * MROWS + er) * PW];
      hr += *(const f32x4*)(pp + ec);
      hz += *(const f32x4*)(pp + 32 + ec);
      hn += *(const f32x4*)(pp + 64 + ec);
    }
    f32x4 hv; u16x4 hb;
#pragma unroll
    for (int i = 0; i < 4; ++i) {
      const float r = sigmf(b2f(xr4[i]) + hr[i]);
      const float z = sigmf(b2f(xz4[i]) + hz[i]);
      const float n = tanhft(b2f(xn4[i]) + r * hn[i]);
      const float v2 = (1.0f - z) * n + z * hp[i];
      hv[i] = v2; hb[i] = f2b(v2);
    }
    *(f32x4*)(hnf + (size_t)b * HID + j0 + ec) = hv;
    *(u16x4*)(hnb + (size_t)b * HID + j0 + ec) = hb;

    // ---- group barrier: flag-array, no RMW ----
    __syncthreads();  // drains vmcnt: all this WG's h stores in L2
    if (tid == 0) {
      __threadfence();  // wbl2: flush XCD L2 to device scope
      __hip_atomic_store(gflags + ig, (unsigned)(t + 1), __ATOMIC_RELEASE,
                         __HIP_MEMORY_SCOPE_AGENT);
    }
    if (tid < 64) {
      for (;;) {
        const unsigned v = __hip_atomic_load(gflags + (tid & 31), __ATOMIC_RELAXED,
                                             __HIP_MEMORY_SCOPE_AGENT);
        if (__all(v >= (unsigned)(t + 1))) break;
        __builtin_amdgcn_s_sleep(2);
      }
      if (tid == 0) __threadfence();  // inv: L1/L2 before reading remote h
    }
    __syncthreads();
  }

  // ---- fused final dense: row b = g*32 + ig (group-local => barrier-safe) ----
  {
    const int br = m0 + ig;
    const int k = tid << 2;
    const f32x4 hvv = *(const f32x4*)(hA + (size_t)br * HID + k);  // t=511 wrote hA
    const f32x4 w0 = *(const f32x4*)(Wd + k);
    const f32x4 w1 = *(const f32x4*)(Wd + HID + k);
    float p0 = hvv.x * w0.x + hvv.y * w0.y + hvv.z * w0.z + hvv.w * w0.w;
    float p1 = hvv.x * w1.x + hvv.y * w1.y + hvv.z * w1.z + hvv.w * w1.w;
#pragma unroll
    for (int off = 32; off > 0; off >>= 1) {
      p0 += __shfl_down(p0, off);
      p1 += __shfl_down(p1, off);
    }
    float* cred = pbuf;  // pbuf free after final __syncthreads
    if (l == 0) { cred[w] = p0; cred[8 + w] = p1; }
    __syncthreads();
    if (tid == 0) out[2 * br]     = cred[0] + cred[1] + cred[2] + cred[3] + bd[0];
    if (tid == 1) out[2 * br + 1] = cred[8] + cred[9] + cred[10] + cred[11] + bd[1];
  }
}

// ---------------- host launch ----------------
extern "C" void kernel_launch(void* const* d_in, const int* in_sizes, int n_in,
                              void* d_out, int out_size, void* d_ws, size_t ws_size,
                              hipStream_t stream) {
  const int*   inputs = (const int*)d_in[0];
  const float* emb = (const float*)d_in[1];
  const float* Wih = (const float*)d_in[2];
  const float* Whh = (const float*)d_in[3];
  const float* bih = (const float*)d_in[4];
  const float* bhh = (const float*)d_in[5];
  const float* Wd  = (const float*)d_in[6];
  const float* bd  = (const float*)d_in[7];

  char* ws = (char*)d_ws;
  unsigned* flags = (unsigned*)ws;                                // [0, 2KB)
  float* hA = (float*)(ws + (size_t)(1 << 20));
  float* hB = (float*)(ws + (size_t)(2 << 20));
  u16* hAb  = (u16*)(ws + (size_t)(3 << 20));
  u16* hBb  = (u16*)(ws + (size_t)(3 << 20) + (size_t)(1 << 19));
  u16* embproj = (u16*)(ws + (size_t)(4 << 20));                  // 196,608,000 B
  u16* embb = (u16*)(ws + 4194304ull + 196608000ull);             // 65,536,000 B
  u16* Wihb = (u16*)(ws + 4194304ull + 196608000ull + 65536000ull);

  // zero flags + h buffers (h0 = 0; flags must start at 0 every launch)
  hipMemsetAsync(d_ws, 0, (size_t)(4 << 20), stream);

  cvt_kernel<<<32000, 256, 0, stream>>>(emb, embb, VOCAB * HID);
  cvt_kernel<<<3072, 256, 0, stream>>>(Wih, Wihb, G3 * HID);
  embproj_gemm<<<250 * 24, 256, 0, stream>>>(embb, Wihb, bih, embproj);

  gru_persist<<<GRP * GWG, 256, 0, stream>>>(inputs, Whh, bhh, embproj, Wd, bd,
                                             hA, hB, hAb, hBb, flags, (float*)d_out);
}

// Round 3
// 4089.410 us; speedup vs baseline: 3.4974x; 2.5526x over previous
//
#include <hip/hip_runtime.h>
#include <stdint.h>
#include <stddef.h>

#define VOCAB 32000
#define HID   1024
#define BATCH 256
#define SEQ   512
#define G3    3072

// gru partitioning: 8 independent groups (heuristically one per XCD via bid&7),
// each group = 32 WGs x (32 batch rows, full 3072 gate cols; 32 hidden cols/WG)
#define GRP   8
#define GWG   32
#define MROWS 32
#define PW    100   // pbuf row stride (floats): 96 cols + 4 pad

typedef unsigned short u16;
typedef unsigned long long u64;
typedef short bf16x8 __attribute__((ext_vector_type(8)));
typedef float f32x4 __attribute__((ext_vector_type(4)));
typedef u16   u16x4 __attribute__((ext_vector_type(4)));

typedef void __attribute__((address_space(1))) gvoid;
typedef void __attribute__((address_space(3))) lvoid;

__device__ __forceinline__ u16 f2b(float f) {
  union { float f; unsigned u; } x; x.f = f;
  return (u16)((x.u + 0x7fffu + ((x.u >> 16) & 1u)) >> 16);
}
__device__ __forceinline__ float b2f(u16 u) {
  union { unsigned u; float f; } x; x.u = ((unsigned)u) << 16;
  return x.f;
}
__device__ __forceinline__ float sigmf(float x) { return 1.0f / (1.0f + __expf(-x)); }
__device__ __forceinline__ float tanhft(float x) { return 1.0f - 2.0f / (__expf(2.0f * x) + 1.0f); }

__device__ __forceinline__ void glds16(const void* g, void* l) {
  __builtin_amdgcn_global_load_lds((gvoid*)g, (lvoid*)l, 16, 0, 0);
}

// cache-bypass (agent-scope relaxed atomic) 8B load/store — no fences anywhere
__device__ __forceinline__ u64 ld_byp(const u16* p) {
  return __hip_atomic_load((const u64*)p, __ATOMIC_RELAXED, __HIP_MEMORY_SCOPE_AGENT);
}
__device__ __forceinline__ void st_byp(u16* p, u64 v) {
  __hip_atomic_store((u64*)p, v, __ATOMIC_RELAXED, __HIP_MEMORY_SCOPE_AGENT);
}
union B16F { u64 u[2]; bf16x8 f; };
union B4U  { u16x4 s; u64 u; };

// ---------------- Phase A0: fp32 -> bf16 conversion ----------------
__global__ __launch_bounds__(256) void cvt_kernel(const float* __restrict__ s,
                                                  u16* __restrict__ d, int n) {
  const int i = (blockIdx.x * 256 + threadIdx.x) * 4;
  if (i + 3 < n) {
    const f32x4 v = *(const f32x4*)(s + i);
    u16x4 o;
    o.x = f2b(v.x); o.y = f2b(v.y); o.z = f2b(v.z); o.w = f2b(v.w);
    *(u16x4*)(d + i) = o;
  }
}

// ---------------- Phase A1: emb_proj = emb_b @ Wih_b^T + b_ih (bf16 out) ----------------
__global__ __launch_bounds__(256) void embproj_gemm(const u16* __restrict__ A,
                                                    const u16* __restrict__ Bm,
                                                    const float* __restrict__ bias,
                                                    u16* __restrict__ C) {
  __shared__ u16 sA[128 * 32];
  __shared__ u16 sB[128 * 32];
  const int tid = threadIdx.x;
  const int w = tid >> 6, l = tid & 63;
  const int wm = w >> 1, wn = w & 1;
  const int m0 = (int)(blockIdx.x / 24) * 128;
  const int n0 = (int)(blockIdx.x % 24) * 128;
  const int row1 = tid >> 2;
  const int kh1  = tid & 3;
  const int kin  = (l >> 4) << 3;
  const int lm   = l & 15;

  f32x4 acc[4][4] = {};
  char* sAb = (char*)sA;
  char* sBb = (char*)sB;

  for (int k0 = 0; k0 < HID; k0 += 32) {
    __syncthreads();
    glds16(A + (size_t)(m0 + row1) * HID + k0 + kh1 * 8,       sAb + w * 1024);
    glds16(A + (size_t)(m0 + 64 + row1) * HID + k0 + kh1 * 8,  sAb + 4096 + w * 1024);
    glds16(Bm + (size_t)(n0 + row1) * HID + k0 + kh1 * 8,      sBb + w * 1024);
    glds16(Bm + (size_t)(n0 + 64 + row1) * HID + k0 + kh1 * 8, sBb + 4096 + w * 1024);
    __syncthreads();
    bf16x8 aF[4], bF[4];
#pragma unroll
    for (int mt = 0; mt < 4; ++mt)
      aF[mt] = *(const bf16x8*)&sA[(64 * wm + 16 * mt + lm) * 32 + kin];
#pragma unroll
    for (int nt = 0; nt < 4; ++nt)
      bF[nt] = *(const bf16x8*)&sB[(64 * wn + 16 * nt + lm) * 32 + kin];
#pragma unroll
    for (int mt = 0; mt < 4; ++mt)
#pragma unroll
      for (int nt = 0; nt < 4; ++nt)
        acc[mt][nt] = __builtin_amdgcn_mfma_f32_16x16x32_bf16(aF[mt], bF[nt], acc[mt][nt], 0, 0, 0);
  }
  __syncthreads();
#pragma unroll
  for (int mt = 0; mt < 4; ++mt)
#pragma unroll
    for (int nt = 0; nt < 4; ++nt) {
      const int col = n0 + 64 * wn + 16 * nt + lm;
      const float bi = bias[col];
      const int rbase = m0 + 64 * wm + 16 * mt + ((l >> 4) << 2);
#pragma unroll
      for (int i = 0; i < 4; ++i)
        C[(size_t)(rbase + i) * G3 + col] = f2b(acc[mt][nt][i] + bi);
    }
}

// ---------------- Phase B: persistent GRU, fence-free flag barrier ----------------
__global__ __launch_bounds__(256, 1) void gru_persist(
    const int* __restrict__ inputs, const float* __restrict__ Whh,
    const float* __restrict__ bhh, const u16* __restrict__ embproj,
    const float* __restrict__ Wd, const float* __restrict__ bd,
    float* __restrict__ hA, float* __restrict__ hB,
    u16* __restrict__ hAb, u16* __restrict__ hBb,
    unsigned* __restrict__ flags, float* __restrict__ out) {
  __shared__ float pbuf[4 * MROWS * PW + 16];  // 51.3 KB

  const int tid = threadIdx.x;
  const int w = tid >> 6, l = tid & 63;
  const int lm = l & 15, kin = (l >> 4) << 3;
  const int bid = blockIdx.x;
  const int g  = bid & 7;    // group (heuristic: XCD id)
  const int ig = bid >> 3;   // 0..31 within group
  const int m0 = g * MROWS;
  const int j0 = ig * 32;    // 32 hidden cols per WG -> 96 gate cols
  unsigned* gflags = flags + g * 64;  // groups 256B apart

  // ---- preload W_hh fragments into registers: 6 col-frags x 8 kk (192 VGPRs) ----
  const int kb = w << 8;  // 256-wide K slice per wave
  bf16x8 wf[6][8];
#pragma unroll
  for (int gg = 0; gg < 6; ++gg) {
    const int gate = gg >> 1;
    const size_t wrow = (size_t)(gate * HID + j0 + ((gg & 1) << 4) + lm) * HID;
#pragma unroll
    for (int kk = 0; kk < 8; ++kk) {
      const float* p = Whh + wrow + kb + (kk << 5) + kin;
      const f32x4 v0 = *(const f32x4*)p;
      const f32x4 v1 = *(const f32x4*)(p + 4);
      bf16x8 f;
      f[0] = (short)f2b(v0.x); f[1] = (short)f2b(v0.y);
      f[2] = (short)f2b(v0.z); f[3] = (short)f2b(v0.w);
      f[4] = (short)f2b(v1.x); f[5] = (short)f2b(v1.y);
      f[6] = (short)f2b(v1.z); f[7] = (short)f2b(v1.w);
      wf[gg][kk] = f;
    }
  }

  // ---- elementwise-phase constants ----
  const int er = tid >> 3;         // row 0..31
  const int ec = (tid & 7) << 2;   // col 0,4,..,28 within 32-col slice
  const int b  = m0 + er;
  const f32x4 brv = *(const f32x4*)(bhh + j0 + ec);
  const f32x4 bzv = *(const f32x4*)(bhh + HID + j0 + ec);
  const f32x4 bnv = *(const f32x4*)(bhh + 2 * HID + j0 + ec);

  for (int t = 0; t < SEQ; ++t) {
    const u16*  hcb = (t & 1) ? hBb : hAb;
    const float* hcf = (t & 1) ? hB : hA;
    float* hnf = (t & 1) ? hA : hB;
    u16*   hnb = (t & 1) ? hAb : hBb;

    // hoisted gathers (cached reads — never invalidated now)
    const int tok = inputs[b * SEQ + t];
    const u16x4 xr4 = *(const u16x4*)(embproj + (size_t)tok * G3 + j0 + ec);
    const u16x4 xz4 = *(const u16x4*)(embproj + (size_t)tok * G3 + HID + j0 + ec);
    const u16x4 xn4 = *(const u16x4*)(embproj + (size_t)tok * G3 + 2 * HID + j0 + ec);
    const f32x4 hp  = *(const f32x4*)(hcf + (size_t)b * HID + j0 + ec);  // WG-private fp32

    // A fragments: cross-WG data -> cache-bypass loads (see IC-coherent values)
    bf16x8 aF[2][8];
#pragma unroll
    for (int m = 0; m < 2; ++m)
#pragma unroll
      for (int kk = 0; kk < 8; ++kk) {
        const u16* p = &hcb[(size_t)(m0 + (m << 4) + lm) * HID + kb + (kk << 5) + kin];
        B16F cv;
        cv.u[0] = ld_byp(p);
        cv.u[1] = ld_byp(p + 4);
        aF[m][kk] = cv.f;
      }

    f32x4 acc[2][6] = {};
#pragma unroll
    for (int kk = 0; kk < 8; ++kk)
#pragma unroll
      for (int m = 0; m < 2; ++m)
#pragma unroll
        for (int gg = 0; gg < 6; ++gg)
          acc[m][gg] = __builtin_amdgcn_mfma_f32_16x16x32_bf16(aF[m][kk], wf[gg][kk], acc[m][gg], 0, 0, 0);

    // partials -> LDS (C layout: col=lane&15, row=(lane>>4)*4+i)
#pragma unroll
    for (int m = 0; m < 2; ++m)
#pragma unroll
      for (int gg = 0; gg < 6; ++gg) {
        const int rl = (m << 4) + ((l >> 4) << 2);
        const int cl = ((gg >> 1) << 5) + ((gg & 1) << 4) + lm;
#pragma unroll
        for (int i = 0; i < 4; ++i)
          pbuf[(w * MROWS + rl + i) * PW + cl] = acc[m][gg][i];
      }
    __syncthreads();

    // cross-wave reduce + gates (32 rows x 32 cols, 4 cells/thread)
    f32x4 hr = brv, hz = bzv, hn = bnv;
#pragma unroll
    for (int ww = 0; ww < 4; ++ww) {
      const float* pp = &pbuf[(ww * MROWS + er) * PW];
      hr += *(const f32x4*)(pp + ec);
      hz += *(const f32x4*)(pp + 32 + ec);
      hn += *(const f32x4*)(pp + 64 + ec);
    }
    f32x4 hv; B4U hbu;
#pragma unroll
    for (int i = 0; i < 4; ++i) {
      const float r = sigmf(b2f(xr4[i]) + hr[i]);
      const float z = sigmf(b2f(xz4[i]) + hz[i]);
      const float n = tanhft(b2f(xn4[i]) + r * hn[i]);
      const float v2 = (1.0f - z) * n + z * hp[i];
      hv[i] = v2; hbu.s[i] = f2b(v2);
    }
    *(f32x4*)(hnf + (size_t)b * HID + j0 + ec) = hv;          // private fp32: cached store
    st_byp(hnb + (size_t)b * HID + j0 + ec, hbu.u);           // shared bf16: write-through

    // ---- group barrier: fence-free ----
    // __syncthreads emits s_waitcnt vmcnt(0) per wave: all h write-through stores
    // are at the coherence point before ANY thread passes, so a relaxed flag
    // store afterward is sufficient release.
    __syncthreads();
    if (tid == 0)
      __hip_atomic_store(gflags + ig, (unsigned)(t + 1), __ATOMIC_RELAXED,
                         __HIP_MEMORY_SCOPE_AGENT);
    if (tid < 64) {
      for (;;) {
        const unsigned v = __hip_atomic_load(gflags + (tid & 31), __ATOMIC_RELAXED,
                                             __HIP_MEMORY_SCOPE_AGENT);
        if (__all(v >= (unsigned)(t + 1))) break;
        __builtin_amdgcn_s_sleep(1);
      }
    }
    __syncthreads();
  }

  // ---- fused final dense on bf16 h (cross-WG columns -> bypass loads) ----
  {
    const int br = m0 + ig;
    const int k = tid << 2;
    B4U hw; hw.u = ld_byp(hAb + (size_t)br * HID + k);  // t=511 wrote hAb
    const f32x4 w0 = *(const f32x4*)(Wd + k);
    const f32x4 w1 = *(const f32x4*)(Wd + HID + k);
    float p0 = 0.f, p1 = 0.f;
#pragma unroll
    for (int i = 0; i < 4; ++i) {
      const float hvv = b2f(hw.s[i]);
      p0 += hvv * ((const float*)&w0)[i];
      p1 += hvv * ((const float*)&w1)[i];
    }
#pragma unroll
    for (int off = 32; off > 0; off >>= 1) {
      p0 += __shfl_down(p0, off);
      p1 += __shfl_down(p1, off);
    }
    float* cred = pbuf;
    if (l == 0) { cred[w] = p0; cred[8 + w] = p1; }
    __syncthreads();
    if (tid == 0) out[2 * br]     = cred[0] + cred[1] + cred[2] + cred[3] + bd[0];
    if (tid == 1) out[2 * br + 1] = cred[8] + cred[9] + cred[10] + cred[11] + bd[1];
  }
}

// ---------------- host launch ----------------
extern "C" void kernel_launch(void* const* d_in, const int* in_sizes, int n_in,
                              void* d_out, int out_size, void* d_ws, size_t ws_size,
                              hipStream_t stream) {
  const int*   inputs = (const int*)d_in[0];
  const float* emb = (const float*)d_in[1];
  const float* Wih = (const float*)d_in[2];
  const float* Whh = (const float*)d_in[3];
  const float* bih = (const float*)d_in[4];
  const float* bhh = (const float*)d_in[5];
  const float* Wd  = (const float*)d_in[6];
  const float* bd  = (const float*)d_in[7];

  char* ws = (char*)d_ws;
  unsigned* flags = (unsigned*)ws;                                // [0, 2KB)
  float* hA = (float*)(ws + (size_t)(1 << 20));
  float* hB = (float*)(ws + (size_t)(2 << 20));
  u16* hAb  = (u16*)(ws + (size_t)(3 << 20));
  u16* hBb  = (u16*)(ws + (size_t)(3 << 20) + (size_t)(1 << 19));
  u16* embproj = (u16*)(ws + (size_t)(4 << 20));                  // 196,608,000 B
  u16* embb = (u16*)(ws + 4194304ull + 196608000ull);             // 65,536,000 B
  u16* Wihb = (u16*)(ws + 4194304ull + 196608000ull + 65536000ull);

  // zero flags + h buffers (h0 = 0; flags must start at 0 every launch)
  hipMemsetAsync(d_ws, 0, (size_t)(4 << 20), stream);

  cvt_kernel<<<32000, 256, 0, stream>>>(emb, embb, VOCAB * HID);
  cvt_kernel<<<3072, 256, 0, stream>>>(Wih, Wihb, G3 * HID);
  embproj_gemm<<<250 * 24, 256, 0, stream>>>(embb, Wihb, bih, embproj);

  gru_persist<<<GRP * GWG, 256, 0, stream>>>(inputs, Whh, bhh, embproj, Wd, bd,
                                             hA, hB, hAb, hBb, flags, (float*)d_out);
}

// Round 4
// 3364.199 us; speedup vs baseline: 4.2513x; 1.2156x over previous
//
#include <hip/hip_runtime.h>
#include <stdint.h>
#include <stddef.h>

#define VOCAB 32000
#define HID   1024
#define BATCH 256
#define SEQ   512
#define G3    3072

// gru partitioning: 8 independent groups (heuristically one per XCD via bid&7),
// each group = 32 WGs x (32 batch rows, full 3072 gate cols; 32 hidden cols/WG)
#define GRP   8
#define GWG   32
#define MROWS 32
#define PW    100   // pbuf row stride (floats): 96 cols + 4 pad
#define CR    40    // staged-chunk row stride (bf16 elems): 32 + 8 pad (80 B, 16B-aligned)

typedef unsigned short u16;
typedef unsigned long long u64;
typedef short bf16x8 __attribute__((ext_vector_type(8)));
typedef float f32x4 __attribute__((ext_vector_type(4)));
typedef u16   u16x4 __attribute__((ext_vector_type(4)));

typedef void __attribute__((address_space(1))) gvoid;
typedef void __attribute__((address_space(3))) lvoid;

__device__ __forceinline__ u16 f2b(float f) {
  union { float f; unsigned u; } x; x.f = f;
  return (u16)((x.u + 0x7fffu + ((x.u >> 16) & 1u)) >> 16);
}
__device__ __forceinline__ float b2f(u16 u) {
  union { unsigned u; float f; } x; x.u = ((unsigned)u) << 16;
  return x.f;
}
__device__ __forceinline__ float sigmf(float x) { return 1.0f / (1.0f + __expf(-x)); }
__device__ __forceinline__ float tanhft(float x) { return 1.0f - 2.0f / (__expf(2.0f * x) + 1.0f); }

__device__ __forceinline__ void glds16(const void* g, void* l) {
  __builtin_amdgcn_global_load_lds((gvoid*)g, (lvoid*)l, 16, 0, 0);
}

// cache-bypass (agent-scope relaxed atomic) 8B load/store — no fences anywhere
__device__ __forceinline__ u64 ld_byp(const u16* p) {
  return __hip_atomic_load((const u64*)p, __ATOMIC_RELAXED, __HIP_MEMORY_SCOPE_AGENT);
}
__device__ __forceinline__ void st_byp(u16* p, u64 v) {
  __hip_atomic_store((u64*)p, v, __ATOMIC_RELAXED, __HIP_MEMORY_SCOPE_AGENT);
}
union B4U { u16x4 s; u64 u; };

// ---------------- Phase A0: fp32 -> bf16 conversion ----------------
__global__ __launch_bounds__(256) void cvt_kernel(const float* __restrict__ s,
                                                  u16* __restrict__ d, int n) {
  const int i = (blockIdx.x * 256 + threadIdx.x) * 4;
  if (i + 3 < n) {
    const f32x4 v = *(const f32x4*)(s + i);
    u16x4 o;
    o.x = f2b(v.x); o.y = f2b(v.y); o.z = f2b(v.z); o.w = f2b(v.w);
    *(u16x4*)(d + i) = o;
  }
}

// ---------------- Phase A1: emb_proj = emb_b @ Wih_b^T + b_ih (bf16 out) ----------------
__global__ __launch_bounds__(256) void embproj_gemm(const u16* __restrict__ A,
                                                    const u16* __restrict__ Bm,
                                                    const float* __restrict__ bias,
                                                    u16* __restrict__ C) {
  __shared__ u16 sA[128 * 32];
  __shared__ u16 sB[128 * 32];
  const int tid = threadIdx.x;
  const int w = tid >> 6, l = tid & 63;
  const int wm = w >> 1, wn = w & 1;
  const int m0 = (int)(blockIdx.x / 24) * 128;
  const int n0 = (int)(blockIdx.x % 24) * 128;
  const int row1 = tid >> 2;
  const int kh1  = tid & 3;
  const int kin  = (l >> 4) << 3;
  const int lm   = l & 15;

  f32x4 acc[4][4] = {};
  char* sAb = (char*)sA;
  char* sBb = (char*)sB;

  for (int k0 = 0; k0 < HID; k0 += 32) {
    __syncthreads();
    glds16(A + (size_t)(m0 + row1) * HID + k0 + kh1 * 8,       sAb + w * 1024);
    glds16(A + (size_t)(m0 + 64 + row1) * HID + k0 + kh1 * 8,  sAb + 4096 + w * 1024);
    glds16(Bm + (size_t)(n0 + row1) * HID + k0 + kh1 * 8,      sBb + w * 1024);
    glds16(Bm + (size_t)(n0 + 64 + row1) * HID + k0 + kh1 * 8, sBb + 4096 + w * 1024);
    __syncthreads();
    bf16x8 aF[4], bF[4];
#pragma unroll
    for (int mt = 0; mt < 4; ++mt)
      aF[mt] = *(const bf16x8*)&sA[(64 * wm + 16 * mt + lm) * 32 + kin];
#pragma unroll
    for (int nt = 0; nt < 4; ++nt)
      bF[nt] = *(const bf16x8*)&sB[(64 * wn + 16 * nt + lm) * 32 + kin];
#pragma unroll
    for (int mt = 0; mt < 4; ++mt)
#pragma unroll
      for (int nt = 0; nt < 4; ++nt)
        acc[mt][nt] = __builtin_amdgcn_mfma_f32_16x16x32_bf16(aF[mt], bF[nt], acc[mt][nt], 0, 0, 0);
  }
  __syncthreads();
#pragma unroll
  for (int mt = 0; mt < 4; ++mt)
#pragma unroll
    for (int nt = 0; nt < 4; ++nt) {
      const int col = n0 + 64 * wn + 16 * nt + lm;
      const float bi = bias[col];
      const int rbase = m0 + 64 * wm + 16 * mt + ((l >> 4) << 2);
#pragma unroll
      for (int i = 0; i < 4; ++i)
        C[(size_t)(rbase + i) * G3 + col] = f2b(acc[mt][nt][i] + bi);
    }
}

// ---------------- Phase B: persistent GRU, per-producer dataflow flags ----------------
__global__ __launch_bounds__(256, 1) void gru_persist(
    const int* __restrict__ inputs, const float* __restrict__ Whh,
    const float* __restrict__ bhh, const u16* __restrict__ embproj,
    const float* __restrict__ Wd, const float* __restrict__ bd,
    u16* __restrict__ hAb, u16* __restrict__ hBb,
    unsigned* __restrict__ flags, float* __restrict__ out) {
  extern __shared__ char smem[];
  u16* sH = (u16*)smem;                         // 4 waves x 8 chunks x 32 rows x CR = 81920 B
  float* pbuf = (float*)(smem + 4 * 8 * 32 * CR * 2);  // [4][32][PW] = 51200 B
  float* cred = pbuf + 4 * MROWS * PW;          // [16]

  const int tid = threadIdx.x;
  const int w = tid >> 6, l = tid & 63;
  const int lm = l & 15, kin = (l >> 4) << 3;
  const int bid = blockIdx.x;
  const int g  = bid & 7;    // group (heuristic: XCD id)
  const int ig = bid >> 3;   // 0..31 within group
  const int m0 = g * MROWS;
  const int j0 = ig * 32;    // 32 hidden cols per WG -> 96 gate cols
  unsigned* gflags = flags + g * 64;  // groups 256B apart

  // ---- preload W_hh fragments into registers: 6 col-frags x 8 kk (192 VGPRs) ----
  const int kb = w << 8;  // 256-wide K slice per wave
  bf16x8 wf[6][8];
#pragma unroll
  for (int gg = 0; gg < 6; ++gg) {
    const int gate = gg >> 1;
    const size_t wrow = (size_t)(gate * HID + j0 + ((gg & 1) << 4) + lm) * HID;
#pragma unroll
    for (int kk = 0; kk < 8; ++kk) {
      const float* p = Whh + wrow + kb + (kk << 5) + kin;
      const f32x4 v0 = *(const f32x4*)p;
      const f32x4 v1 = *(const f32x4*)(p + 4);
      bf16x8 f;
      f[0] = (short)f2b(v0.x); f[1] = (short)f2b(v0.y);
      f[2] = (short)f2b(v0.z); f[3] = (short)f2b(v0.w);
      f[4] = (short)f2b(v1.x); f[5] = (short)f2b(v1.y);
      f[6] = (short)f2b(v1.z); f[7] = (short)f2b(v1.w);
      wf[gg][kk] = f;
    }
  }

  // ---- staging geometry (loop-invariant) ----
  u16* sHw = sH + w * (8 * 32 * CR);           // wave-private staging region
  const int srow = l >> 3;                      // 0..7 (global row within 8-row block)
  const int scol = (l & 7) << 2;                // 0,4,..,28 (elem col within 32-chunk)
  // ds_read fragment addresses: chunk kk, row 16m+lm, col-in-chunk kin

  // ---- elementwise-phase constants ----
  const int er = tid >> 3;         // row 0..31
  const int ec = (tid & 7) << 2;   // col 0,4,..,28 within 32-col slice
  const int b  = m0 + er;
  const f32x4 brv = *(const f32x4*)(bhh + j0 + ec);
  const f32x4 bzv = *(const f32x4*)(bhh + HID + j0 + ec);
  const f32x4 bnv = *(const f32x4*)(bhh + 2 * HID + j0 + ec);

  f32x4 hreg = {0.f, 0.f, 0.f, 0.f};  // this thread's 4 fp32 h cells (h0 = 0)

  for (int t = 0; t < SEQ; ++t) {
    const u16* hcb = (t & 1) ? hBb : hAb;
    u16*       hnb = (t & 1) ? hAb : hBb;

    // prefetch gathers for this step (independent of h / flags)
    const int tok = inputs[b * SEQ + t];
    const u16x4 xr4 = *(const u16x4*)(embproj + (size_t)tok * G3 + j0 + ec);
    const u16x4 xz4 = *(const u16x4*)(embproj + (size_t)tok * G3 + HID + j0 + ec);
    const u16x4 xn4 = *(const u16x4*)(embproj + (size_t)tok * G3 + 2 * HID + j0 + ec);

    // ---- per-wave poll: only this wave's 8 producers (cols kb..kb+255) ----
    if (t) {
      const unsigned want = (unsigned)t;
      for (;;) {
        const unsigned v = __hip_atomic_load(gflags + (w << 3) + (l & 7), __ATOMIC_RELAXED,
                                             __HIP_MEMORY_SCOPE_AGENT);
        if (__all(v >= want)) break;
        __builtin_amdgcn_s_sleep(1);
      }
    }

    // ---- coalesced staging: 32 rows x 256 cols (this wave's K slice) -> LDS ----
    u64 stg[8][4];
#pragma unroll
    for (int j = 0; j < 8; ++j)
#pragma unroll
      for (int q = 0; q < 4; ++q)
        stg[j][q] = ld_byp(hcb + (size_t)(m0 + (q << 3) + srow) * HID + kb + (j << 5) + scol);
#pragma unroll
    for (int j = 0; j < 8; ++j)
#pragma unroll
      for (int q = 0; q < 4; ++q)
        *(u64*)&sHw[((j << 5) + (q << 3) + srow) * CR + scol] = stg[j][q];

    // ---- MFMA: 2 m-tiles x 6 gate-frags x 8 K-chunks ----
    f32x4 acc[2][6] = {};
#pragma unroll
    for (int kk = 0; kk < 8; ++kk) {
      const bf16x8 a0 = *(const bf16x8*)&sHw[((kk << 5) + lm) * CR + kin];
      const bf16x8 a1 = *(const bf16x8*)&sHw[((kk << 5) + 16 + lm) * CR + kin];
#pragma unroll
      for (int gg = 0; gg < 6; ++gg) {
        acc[0][gg] = __builtin_amdgcn_mfma_f32_16x16x32_bf16(a0, wf[gg][kk], acc[0][gg], 0, 0, 0);
        acc[1][gg] = __builtin_amdgcn_mfma_f32_16x16x32_bf16(a1, wf[gg][kk], acc[1][gg], 0, 0, 0);
      }
    }

    // partials -> LDS (C layout: col=lane&15, row=(lane>>4)*4+i)
#pragma unroll
    for (int m = 0; m < 2; ++m)
#pragma unroll
      for (int gg = 0; gg < 6; ++gg) {
        const int rl = (m << 4) + ((l >> 4) << 2);
        const int cl = ((gg >> 1) << 5) + ((gg & 1) << 4) + lm;
#pragma unroll
        for (int i = 0; i < 4; ++i)
          pbuf[(w * MROWS + rl + i) * PW + cl] = acc[m][gg][i];
      }
    __syncthreads();

    // cross-wave reduce + gates (32 rows x 32 cols, 4 cells/thread)
    f32x4 hr = brv, hz = bzv, hn = bnv;
#pragma unroll
    for (int ww = 0; ww < 4; ++ww) {
      const float* pp = &pbuf[(ww * MROWS + er) * PW];
      hr += *(const f32x4*)(pp + ec);
      hz += *(const f32x4*)(pp + 32 + ec);
      hn += *(const f32x4*)(pp + 64 + ec);
    }
    f32x4 hv; B4U hbu;
#pragma unroll
    for (int i = 0; i < 4; ++i) {
      const float r = sigmf(b2f(xr4[i]) + hr[i]);
      const float z = sigmf(b2f(xz4[i]) + hz[i]);
      const float n = tanhft(b2f(xn4[i]) + r * hn[i]);
      const float v2 = (1.0f - z) * n + z * hreg[i];
      hv[i] = v2; hbu.s[i] = f2b(v2);
    }
    hreg = hv;                                          // fp32 h stays in registers
    st_byp(hnb + (size_t)b * HID + j0 + ec, hbu.u);     // shared bf16: write-through

    // ---- producer flag: WG-wide h stores drained by syncthreads (vmcnt 0) ----
    __syncthreads();
    if (tid == 0)
      __hip_atomic_store(gflags + ig, (unsigned)(t + 1), __ATOMIC_RELAXED,
                         __HIP_MEMORY_SCOPE_AGENT);
  }

  // ---- wait for whole group, then fused final dense on bf16 h ----
  {
    for (;;) {
      const unsigned v = __hip_atomic_load(gflags + (l & 31), __ATOMIC_RELAXED,
                                           __HIP_MEMORY_SCOPE_AGENT);
      if (__all(v >= (unsigned)SEQ)) break;
      __builtin_amdgcn_s_sleep(1);
    }
    const int br = m0 + ig;
    const int k = tid << 2;
    B4U hw; hw.u = ld_byp(hAb + (size_t)br * HID + k);  // t=511 wrote hAb
    const f32x4 w0 = *(const f32x4*)(Wd + k);
    const f32x4 w1 = *(const f32x4*)(Wd + HID + k);
    float p0 = 0.f, p1 = 0.f;
#pragma unroll
    for (int i = 0; i < 4; ++i) {
      const float hvv = b2f(hw.s[i]);
      p0 += hvv * ((const float*)&w0)[i];
      p1 += hvv * ((const float*)&w1)[i];
    }
#pragma unroll
    for (int off = 32; off > 0; off >>= 1) {
      p0 += __shfl_down(p0, off);
      p1 += __shfl_down(p1, off);
    }
    if (l == 0) { cred[w] = p0; cred[8 + w] = p1; }
    __syncthreads();
    if (tid == 0) out[2 * br]     = cred[0] + cred[1] + cred[2] + cred[3] + bd[0];
    if (tid == 1) out[2 * br + 1] = cred[8] + cred[9] + cred[10] + cred[11] + bd[1];
  }
}

// ---------------- host launch ----------------
extern "C" void kernel_launch(void* const* d_in, const int* in_sizes, int n_in,
                              void* d_out, int out_size, void* d_ws, size_t ws_size,
                              hipStream_t stream) {
  const int*   inputs = (const int*)d_in[0];
  const float* emb = (const float*)d_in[1];
  const float* Wih = (const float*)d_in[2];
  const float* Whh = (const float*)d_in[3];
  const float* bih = (const float*)d_in[4];
  const float* bhh = (const float*)d_in[5];
  const float* Wd  = (const float*)d_in[6];
  const float* bd  = (const float*)d_in[7];

  char* ws = (char*)d_ws;
  unsigned* flags = (unsigned*)ws;                                  // [0, 2KB)
  u16* hAb = (u16*)(ws + (size_t)(1 << 20));                        // 512 KB
  u16* hBb = (u16*)(ws + (size_t)(1 << 20) + (size_t)(1 << 19));    // 512 KB
  u16* embproj = (u16*)(ws + (size_t)(2 << 20));                    // 196,608,000 B
  u16* embb = (u16*)(ws + 2097152ull + 196608000ull);               // 65,536,000 B
  u16* Wihb = (u16*)(ws + 2097152ull + 196608000ull + 65536000ull); // 6,291,456 B

  // zero flags + h bf16 double buffers (h0 = 0; flags must start 0 every launch)
  hipMemsetAsync(d_ws, 0, (size_t)(2 << 20), stream);

  cvt_kernel<<<32000, 256, 0, stream>>>(emb, embb, VOCAB * HID);
  cvt_kernel<<<3072, 256, 0, stream>>>(Wih, Wihb, G3 * HID);
  embproj_gemm<<<250 * 24, 256, 0, stream>>>(embb, Wihb, bih, embproj);

  const int smem_bytes = 4 * 8 * 32 * CR * 2 + 4 * MROWS * PW * 4 + 64;  // 133,248 B
  (void)hipFuncSetAttribute((const void*)gru_persist,
                            hipFuncAttributeMaxDynamicSharedMemorySize, smem_bytes);
  gru_persist<<<GRP * GWG, 256, smem_bytes, stream>>>(inputs, Whh, bhh, embproj, Wd, bd,
                                                      hAb, hBb, flags, (float*)d_out);
}